// Round 1
// 282.900 us; speedup vs baseline: 1.1603x; 1.1603x over previous
//
#include <hip/hip_runtime.h>
#include <math.h>

// IDCT2 (DCT-III, ortho) over (16,32,256,256) fp32 via bf16 MFMA.
// Z = M * X * M^T, M[n][k] = w[k]*cos(pi*k*(2n+1)/512).
//
// Round-N: FUSED kernel — one block per 256x256 batch.
//   Stage 1: W^T[n][i] = sum_k X[i][k] M[n][k]  -> bf16 in LDS (XOR-swizzled)
//   Stage 2: Z[m][n]   = sum_i M[m][i] W[i][n]  (A = W^T rows, B = M rows)
// Eliminates the 134 MB Yt HBM round-trip of the 2-pass version.
// LDS: Xs[256][40] (20.5 KB staging) + Wt 256x512B (128 KB) = 148 KB dynamic.

constexpr int N = 256;
typedef __attribute__((ext_vector_type(8))) short short8;
typedef __attribute__((ext_vector_type(4))) float f32x4;

constexpr int XS_STRIDE = 40;                       // ushorts per row (bank-safe)
constexpr size_t XS_BYTES = (size_t)N * XS_STRIDE * 2;   // 20480
constexpr size_t WT_BYTES = (size_t)N * N * 2;           // 131072
constexpr size_t FUSED_LDS = XS_BYTES + WT_BYTES;        // 151552

__device__ __forceinline__ unsigned short f2bf(float f) {
    unsigned int u = __float_as_uint(f);
    u += 0x7fffu + ((u >> 16) & 1u);
    return (unsigned short)(u >> 16);
}

__device__ __forceinline__ float mvalf(int n, int k) {
    const float CST = 0.006135923151542565f;  // pi/512
    const float W0  = 0.0625f;                // 1/sqrt(256)
    const float WK  = 0.08838834764831845f;   // sqrt(2/256)
    int q = (k * (2 * n + 1)) & 1023;
    return ((k == 0) ? W0 : WK) * __cosf(CST * (float)q);
}

__global__ __launch_bounds__(256) void mgen(unsigned short* __restrict__ Mg) {
    int idx = blockIdx.x * 256 + threadIdx.x;
    int n = idx >> 8, k = idx & 255;
    Mg[idx] = f2bf(mvalf(n, k));
}

// W^T LDS addressing: row n (512 B), byte col = i*2, XOR-swizzle bits [6:4]
// with n&7 so 16-lane column reads spread over all 8 16B-slots of a 128B line.
__device__ __forceinline__ int wt_off(int n, int i2) {
    return n * 512 + (i2 ^ ((n & 7) << 4));
}

__global__ __launch_bounds__(1024) void idct_fused(
        const float* __restrict__ X,
        const unsigned short* __restrict__ Mg,
        float* __restrict__ Z) {
    extern __shared__ __align__(16) unsigned char smem[];
    unsigned short* Xs = (unsigned short*)smem;          // [256][40] bf16
    unsigned char*  Wt = smem + XS_BYTES;                // 256 rows x 512 B, swizzled

    const float* Xb = X + (size_t)blockIdx.x * N * N;
    float*       Zb = Z + (size_t)blockIdx.x * N * N;

    const int tid = threadIdx.x;
    const int w  = tid >> 6, l = tid & 63;
    const int q  = l >> 4, lr = l & 15;
    const int wr = w >> 2, wc = w & 3;    // 4x4 wave grid, 64x64 tiles

    // Staging map: thread stages 8 fp32 of X: row = tid>>2, col = (tid&3)*8.
    const int srow = tid >> 2, scol = (tid & 3) * 8;
    const float* xsrc = Xb + (size_t)srow * N + scol;

    f32x4 acc[4][4];
    #pragma unroll
    for (int r = 0; r < 4; ++r)
        #pragma unroll
        for (int c = 0; c < 4; ++c) acc[r][c] = f32x4{0.f, 0.f, 0.f, 0.f};

    // ---------------- Stage 1: W^T = (X * M^T)^T into LDS ----------------
    // Depth-1 register prefetch: loads for k-tile t+1 issue during compute of t.
    float4 u0 = ((const float4*)xsrc)[0];
    float4 u1 = ((const float4*)xsrc)[1];

    #pragma unroll 1
    for (int kt = 0; kt < 8; ++kt) {
        const int k0 = kt * 32;
        if (kt) __syncthreads();          // prior k-tile's readers done
        ushort4 p0 = {f2bf(u0.x), f2bf(u0.y), f2bf(u0.z), f2bf(u0.w)};
        ushort4 p1 = {f2bf(u1.x), f2bf(u1.y), f2bf(u1.z), f2bf(u1.w)};
        *(ushort4*)&Xs[srow * XS_STRIDE + scol + 0] = p0;
        *(ushort4*)&Xs[srow * XS_STRIDE + scol + 4] = p1;
        __syncthreads();
        if (kt < 7) {                     // prefetch next k-tile (hides HBM latency)
            u0 = ((const float4*)(xsrc + k0 + 32))[0];
            u1 = ((const float4*)(xsrc + k0 + 32))[1];
        }
        short8 bfr[4], afr[4];
        #pragma unroll
        for (int c = 0; c < 4; ++c)       // M rows (n), L2-resident global
            bfr[c] = *(const short8*)&Mg[(wc * 64 + c * 16 + lr) * N + k0 + q * 8];
        #pragma unroll
        for (int r = 0; r < 4; ++r)       // X rows (i) from LDS
            afr[r] = *(const short8*)&Xs[(wr * 64 + r * 16 + lr) * XS_STRIDE + q * 8];
        #pragma unroll
        for (int r = 0; r < 4; ++r)
            #pragma unroll
            for (int c = 0; c < 4; ++c)
                acc[r][c] = __builtin_amdgcn_mfma_f32_16x16x32_bf16(
                    afr[r], bfr[c], acc[r][c], 0, 0, 0);
    }

    // Epilogue: acc[r][c][j] = W[i = wr*64+r*16+q*4+j][n = wc*64+c*16+lr].
    // Write W^T[n][i] bf16, swizzled. Disjoint from Xs -> no barrier needed first.
    #pragma unroll
    for (int r = 0; r < 4; ++r)
        #pragma unroll
        for (int c = 0; c < 4; ++c) {
            ushort4 pw = {f2bf(acc[r][c][0]), f2bf(acc[r][c][1]),
                          f2bf(acc[r][c][2]), f2bf(acc[r][c][3])};
            int n  = wc * 64 + c * 16 + lr;
            int i2 = (wr * 64 + r * 16 + q * 4) * 2;
            *(ushort4*)(Wt + wt_off(n, i2)) = pw;
        }
    __syncthreads();

    // ---------------- Stage 2: Z = M * W (barrier-free) ----------------
    // A = W^T rows (n, i-contig) from LDS; B = M rows (m, i-contig) from L2.
    // acc2[r][c][j] = Z[m = wc*64+c*16+lr][n = wr*64+r*16+q*4+j]
    f32x4 acc2[4][4];
    #pragma unroll
    for (int r = 0; r < 4; ++r)
        #pragma unroll
        for (int c = 0; c < 4; ++c) acc2[r][c] = f32x4{0.f, 0.f, 0.f, 0.f};

    #pragma unroll 2
    for (int it = 0; it < 8; ++it) {
        const int i0 = it * 32;
        short8 af[4], bf[4];
        #pragma unroll
        for (int c = 0; c < 4; ++c)
            bf[c] = *(const short8*)&Mg[(wc * 64 + c * 16 + lr) * N + i0 + q * 8];
        #pragma unroll
        for (int r = 0; r < 4; ++r) {
            int n = wr * 64 + r * 16 + lr;
            af[r] = *(const short8*)(Wt + wt_off(n, (i0 + q * 8) * 2));
        }
        #pragma unroll
        for (int r = 0; r < 4; ++r)
            #pragma unroll
            for (int c = 0; c < 4; ++c)
                acc2[r][c] = __builtin_amdgcn_mfma_f32_16x16x32_bf16(
                    af[r], bf[c], acc2[r][c], 0, 0, 0);
    }

    // Direct coalesced store: lane owns 4 n-contiguous fp32 per (r,c).
    #pragma unroll
    for (int r = 0; r < 4; ++r)
        #pragma unroll
        for (int c = 0; c < 4; ++c) {
            float4 v = make_float4(acc2[r][c][0], acc2[r][c][1],
                                   acc2[r][c][2], acc2[r][c][3]);
            int m = wc * 64 + c * 16 + lr;
            int n = wr * 64 + r * 16 + q * 4;
            *(float4*)(Zb + (size_t)m * N + n) = v;
        }
}

// ================= 2-pass bf16 path (fallback #1, round-3 kernels) =========
__global__ __launch_bounds__(256) void gemm_p1(const float* __restrict__ X,
                                               const unsigned short* __restrict__ Mg,
                                               unsigned short* __restrict__ Yt) {
    const int n0 = blockIdx.x * 128;
    const int i0 = blockIdx.y * 128;
    const float* Xb = X + (size_t)blockIdx.z * N * N;
    unsigned short* Ytb = Yt + (size_t)blockIdx.z * N * N;

    __shared__ union {
        struct { unsigned short A[128][40]; unsigned short B[128][40]; } s;
        unsigned short T[128][72];
    } sm;

    const int tid = threadIdx.x;
    const int w = tid >> 6, l = tid & 63;
    const int q = l >> 4, lr = l & 15;
    const int wr = w >> 1, wc = w & 1;
    const int sr = tid >> 1, sh = tid & 1;

    f32x4 acc[4][4];
    #pragma unroll
    for (int r = 0; r < 4; ++r)
        #pragma unroll
        for (int c = 0; c < 4; ++c) acc[r][c] = f32x4{0.f, 0.f, 0.f, 0.f};

    for (int k0 = 0; k0 < N; k0 += 32) {
        {
            const float* src = Xb + (size_t)(i0 + sr) * N + k0 + sh * 16;
            float4 v0 = ((const float4*)src)[0];
            float4 v1 = ((const float4*)src)[1];
            float4 v2 = ((const float4*)src)[2];
            float4 v3 = ((const float4*)src)[3];
            ushort4 p0 = {f2bf(v0.x), f2bf(v0.y), f2bf(v0.z), f2bf(v0.w)};
            ushort4 p1 = {f2bf(v1.x), f2bf(v1.y), f2bf(v1.z), f2bf(v1.w)};
            ushort4 p2 = {f2bf(v2.x), f2bf(v2.y), f2bf(v2.z), f2bf(v2.w)};
            ushort4 p3 = {f2bf(v3.x), f2bf(v3.y), f2bf(v3.z), f2bf(v3.w)};
            *(ushort4*)&sm.s.A[sr][sh * 16 + 0]  = p0;
            *(ushort4*)&sm.s.A[sr][sh * 16 + 4]  = p1;
            *(ushort4*)&sm.s.A[sr][sh * 16 + 8]  = p2;
            *(ushort4*)&sm.s.A[sr][sh * 16 + 12] = p3;
        }
        {
            const unsigned short* src = Mg + (n0 + sr) * N + k0 + sh * 16;
            uint4 m0 = ((const uint4*)src)[0];
            uint4 m1 = ((const uint4*)src)[1];
            *(uint4*)&sm.s.B[sr][sh * 16 + 0] = m0;
            *(uint4*)&sm.s.B[sr][sh * 16 + 8] = m1;
        }
        __syncthreads();
        short8 afr[4], bfr[4];
        #pragma unroll
        for (int r = 0; r < 4; ++r)
            afr[r] = *(const short8*)&sm.s.A[wr * 64 + r * 16 + lr][q * 8];
        #pragma unroll
        for (int c = 0; c < 4; ++c)
            bfr[c] = *(const short8*)&sm.s.B[wc * 64 + c * 16 + lr][q * 8];
        #pragma unroll
        for (int r = 0; r < 4; ++r)
            #pragma unroll
            for (int c = 0; c < 4; ++c)
                acc[r][c] = __builtin_amdgcn_mfma_f32_16x16x32_bf16(
                    afr[r], bfr[c], acc[r][c], 0, 0, 0);
        __syncthreads();
    }

    #pragma unroll
    for (int ch = 0; ch < 2; ++ch) {
        if (wr == ch) {
            #pragma unroll
            for (int r = 0; r < 4; ++r)
                #pragma unroll
                for (int c = 0; c < 4; ++c) {
                    ushort4 p = {f2bf(acc[r][c][0]), f2bf(acc[r][c][1]),
                                 f2bf(acc[r][c][2]), f2bf(acc[r][c][3])};
                    *(ushort4*)&sm.T[wc * 64 + c * 16 + lr][r * 16 + q * 4] = p;
                }
        }
        __syncthreads();
        {
            int row = tid >> 1, hh = tid & 1;
            unsigned short* dst = Ytb + (size_t)(n0 + row) * N + i0 + ch * 64 + hh * 32;
            const uint4* s4 = (const uint4*)&sm.T[row][hh * 32];
            uint4 a0 = s4[0], a1 = s4[1], a2 = s4[2], a3 = s4[3];
            ((uint4*)dst)[0] = a0; ((uint4*)dst)[1] = a1;
            ((uint4*)dst)[2] = a2; ((uint4*)dst)[3] = a3;
        }
        __syncthreads();
    }
}

__global__ __launch_bounds__(256) void gemm_p2(const unsigned short* __restrict__ Yt,
                                               const unsigned short* __restrict__ Mg,
                                               float* __restrict__ Z) {
    const int m0 = blockIdx.x * 128;
    const int n0 = blockIdx.y * 128;
    const unsigned short* Ytb = Yt + (size_t)blockIdx.z * N * N;
    float* Zb = Z + (size_t)blockIdx.z * N * N;

    __shared__ union {
        struct { unsigned short A[128][40]; unsigned short B[128][40]; } s;
        float T[32][132];
    } sm;

    const int tid = threadIdx.x;
    const int w = tid >> 6, l = tid & 63;
    const int q = l >> 4, lr = l & 15;
    const int wr = w >> 1, wc = w & 1;
    const int sr = tid >> 1, sh = tid & 1;

    f32x4 acc[4][4];
    #pragma unroll
    for (int r = 0; r < 4; ++r)
        #pragma unroll
        for (int c = 0; c < 4; ++c) acc[r][c] = f32x4{0.f, 0.f, 0.f, 0.f};

    for (int k0 = 0; k0 < N; k0 += 32) {
        {
            const unsigned short* src = Ytb + (size_t)(n0 + sr) * N + k0 + sh * 16;
            uint4 a0 = ((const uint4*)src)[0];
            uint4 a1 = ((const uint4*)src)[1];
            *(uint4*)&sm.s.A[sr][sh * 16 + 0] = a0;
            *(uint4*)&sm.s.A[sr][sh * 16 + 8] = a1;
        }
        {
            const unsigned short* src = Mg + (m0 + sr) * N + k0 + sh * 16;
            uint4 m0v = ((const uint4*)src)[0];
            uint4 m1v = ((const uint4*)src)[1];
            *(uint4*)&sm.s.B[sr][sh * 16 + 0] = m0v;
            *(uint4*)&sm.s.B[sr][sh * 16 + 8] = m1v;
        }
        __syncthreads();
        short8 afr[4], bfr[4];
        #pragma unroll
        for (int r = 0; r < 4; ++r)
            afr[r] = *(const short8*)&sm.s.A[wr * 64 + r * 16 + lr][q * 8];
        #pragma unroll
        for (int c = 0; c < 4; ++c)
            bfr[c] = *(const short8*)&sm.s.B[wc * 64 + c * 16 + lr][q * 8];
        #pragma unroll
        for (int r = 0; r < 4; ++r)
            #pragma unroll
            for (int c = 0; c < 4; ++c)
                acc[r][c] = __builtin_amdgcn_mfma_f32_16x16x32_bf16(
                    afr[r], bfr[c], acc[r][c], 0, 0, 0);
        __syncthreads();
    }

    #pragma unroll
    for (int ch = 0; ch < 4; ++ch) {
        if (wc == (ch >> 1)) {
            #pragma unroll
            for (int cc = 0; cc < 2; ++cc) {
                int c = (ch & 1) * 2 + cc;
                int mp = cc * 16 + lr;
                #pragma unroll
                for (int r = 0; r < 4; ++r) {
                    float4 p = {acc[r][c][0], acc[r][c][1], acc[r][c][2], acc[r][c][3]};
                    *(float4*)&sm.T[mp][wr * 64 + r * 16 + q * 4] = p;
                }
            }
        }
        __syncthreads();
        {
            int row = tid >> 3, seg = tid & 7;
            float* dst = Zb + (size_t)(m0 + ch * 32 + row) * N + n0 + seg * 16;
            const float4* s4 = (const float4*)&sm.T[row][seg * 16];
            float4 a0 = s4[0], a1 = s4[1], a2 = s4[2], a3 = s4[3];
            ((float4*)dst)[0] = a0; ((float4*)dst)[1] = a1;
            ((float4*)dst)[2] = a2; ((float4*)dst)[3] = a3;
        }
        __syncthreads();
    }
}

// ================= fp32 fallback (ws too small) — round-1 kernels =========
__global__ __launch_bounds__(256) void idct_cols(const float* __restrict__ X,
                                                 float* __restrict__ Y) {
    const int n0 = blockIdx.x * 64;
    const int i0 = blockIdx.y * 64;
    const float* Xb = X + (size_t)blockIdx.z * N * N;
    float* Yb = Y + (size_t)blockIdx.z * N * N;
    __shared__ float Ast[16][68];
    __shared__ float Bs[16][68];
    const int tid = threadIdx.x;
    const int tx = tid & 15, ty = tid >> 4;
    float acc[4][4] = {};
    for (int k0 = 0; k0 < N; k0 += 16) {
        {
            int r = tid >> 2, c4 = (tid & 3) << 2;
            float4 v = *reinterpret_cast<const float4*>(Xb + (size_t)(i0 + r) * N + k0 + c4);
            Ast[c4 + 0][r] = v.x; Ast[c4 + 1][r] = v.y;
            Ast[c4 + 2][r] = v.z; Ast[c4 + 3][r] = v.w;
        }
        #pragma unroll
        for (int j = 0; j < 4; ++j) {
            int ll = tid + 256 * j;
            Bs[ll >> 6][ll & 63] = mvalf(n0 + (ll & 63), k0 + (ll >> 6));
        }
        __syncthreads();
        #pragma unroll
        for (int kk = 0; kk < 16; ++kk) {
            float4 av = *reinterpret_cast<const float4*>(&Ast[kk][ty << 2]);
            float4 bv = *reinterpret_cast<const float4*>(&Bs[kk][tx << 2]);
            float a[4] = {av.x, av.y, av.z, av.w};
            float bb[4] = {bv.x, bv.y, bv.z, bv.w};
            #pragma unroll
            for (int r = 0; r < 4; ++r)
                #pragma unroll
                for (int c = 0; c < 4; ++c) acc[r][c] += a[r] * bb[c];
        }
        __syncthreads();
    }
    #pragma unroll
    for (int r = 0; r < 4; ++r) {
        float4 v = make_float4(acc[r][0], acc[r][1], acc[r][2], acc[r][3]);
        *reinterpret_cast<float4*>(Yb + (size_t)(i0 + (ty << 2) + r) * N + n0 + (tx << 2)) = v;
    }
}

__global__ __launch_bounds__(512) void idct_rows_inplace(float* __restrict__ Y) {
    const int n0 = blockIdx.x * 64;
    float* Yb = Y + (size_t)blockIdx.y * N * N;
    __shared__ float Ys[256][68];
    __shared__ float Ms[16][256];
    const int tid = threadIdx.x;
    #pragma unroll
    for (int j = 0; j < 8; ++j) {
        int ll = tid + 512 * j;
        int row = ll >> 4, c4 = (ll & 15) << 2;
        *reinterpret_cast<float4*>(&Ys[row][c4]) =
            *reinterpret_cast<const float4*>(Yb + (size_t)row * N + n0 + c4);
    }
    __syncthreads();
    const int tx = tid & 15, ty = tid >> 4;
    float acc[8][4] = {};
    for (int i0 = 0; i0 < N; i0 += 16) {
        __syncthreads();
        #pragma unroll
        for (int j = 0; j < 8; ++j) {
            int ll = tid + 512 * j;
            Ms[ll >> 8][ll & 255] = mvalf(ll & 255, i0 + (ll >> 8));
        }
        __syncthreads();
        #pragma unroll
        for (int ii = 0; ii < 16; ++ii) {
            float bb[4];
            #pragma unroll
            for (int c = 0; c < 4; ++c) bb[c] = Ys[i0 + ii][(tx << 2) + c];
            #pragma unroll
            for (int r = 0; r < 8; ++r) {
                float a = Ms[ii][(ty << 3) + r];
                #pragma unroll
                for (int c = 0; c < 4; ++c) acc[r][c] += a * bb[c];
            }
        }
    }
    #pragma unroll
    for (int r = 0; r < 8; ++r) {
        float4 v = make_float4(acc[r][0], acc[r][1], acc[r][2], acc[r][3]);
        *reinterpret_cast<float4*>(Yb + (size_t)((ty << 3) + r) * N + n0 + (tx << 2)) = v;
    }
}

extern "C" void kernel_launch(void* const* d_in, const int* in_sizes, int n_in,
                              void* d_out, int out_size, void* d_ws, size_t ws_size,
                              hipStream_t stream) {
    const float* X = (const float*)d_in[0];
    float* out = (float*)d_out;
    const int total = in_sizes[0];
    const int Bn = total / (N * N);   // 512
    const size_t needM  = (size_t)N * N * 2;               // M bf16
    const size_t need2p = needM + (size_t)total * 2;       // M + Yt bf16

    // One-time: raise dynamic-LDS cap for the fused kernel (host-side, not a
    // stream op -> safe under graph capture). Fall back to 2-pass on failure.
    static int fused_ok = -1;
    if (fused_ok < 0) {
        hipError_t e = hipFuncSetAttribute(
            reinterpret_cast<const void*>(idct_fused),
            hipFuncAttributeMaxDynamicSharedMemorySize, (int)FUSED_LDS);
        fused_ok = (e == hipSuccess) ? 1 : 0;
    }

    if (fused_ok == 1 && ws_size >= needM) {
        unsigned short* Mg = (unsigned short*)d_ws;
        mgen<<<N * N / 256, 256, 0, stream>>>(Mg);
        idct_fused<<<dim3(Bn), 1024, FUSED_LDS, stream>>>(X, Mg, out);
    } else if (ws_size >= need2p) {
        unsigned short* Mg = (unsigned short*)d_ws;
        unsigned short* Yt = Mg + N * N;
        mgen<<<N * N / 256, 256, 0, stream>>>(Mg);
        gemm_p1<<<dim3(2, 2, Bn), 256, 0, stream>>>(X, Mg, Yt);
        gemm_p2<<<dim3(2, 2, Bn), 256, 0, stream>>>(Yt, Mg, out);
    } else {
        idct_cols<<<dim3(N / 64, N / 64, Bn), 256, 0, stream>>>(X, out);
        idct_rows_inplace<<<dim3(N / 64, Bn), 512, 0, stream>>>(out);
    }
}